// Round 7
// baseline (106.353 us; speedup 1.0000x reference)
//
#include <hip/hip_runtime.h>
#include <hip/hip_bf16.h>
#include <stdint.h>

#define LOG2E 1.4426950408889634f

typedef float f32x4 __attribute__((ext_vector_type(4)));
typedef short s16x8 __attribute__((ext_vector_type(8)));

__device__ __forceinline__ float bf2f(uint16_t u) {
    uint32_t x = ((uint32_t)u) << 16;
    float f;
    __builtin_memcpy(&f, &x, 4);
    return f;
}
__device__ __forceinline__ uint16_t f2bf(float f) {
    uint32_t x;
    __builtin_memcpy(&x, &f, 4);
    uint32_t r = (x + 0x7fffu + ((x >> 16) & 1u)) >> 16;
    return (uint16_t)r;
}

// -------------------- Kernel 0: split W (fp32) into hi/lo bf16 --------------------
__global__ __launch_bounds__(256) void k0_splitW(
    const float* __restrict__ W, uint16_t* __restrict__ whi, uint16_t* __restrict__ wlo)
{
    int i = blockIdx.x * 256 + threadIdx.x;
    float x = W[i];
    uint16_t hb = f2bf(x);
    whi[i] = hb;
    wlo[i] = f2bf(x - bf2f(hb));
}

// -------------------- Kernel 1: Wh via split-bf16 MFMA; whB frag-order; s1/s2; rowgroup max ---
// 1024 blocks x 256 thr (4 waves). Block = 16 rows (R0=blockIdx*16); wave w = f-quarter (32 f).
// whB elem (f, j): fblk=f>>4, jt=(j&1023)>>5, lane=((j>>3)&3)*16+(f&15), t=j&7
//   offset = b*131072 + fblk*16384 + jt*512 + lane*8 + t   (k2's B-load: lane*16B coalesced)
__global__ __launch_bounds__(256) void k1_gemm(
    const float* __restrict__ h, const uint16_t* __restrict__ whi_,
    const uint16_t* __restrict__ wlo_,
    const float* __restrict__ aw, const float* __restrict__ ab,
    uint16_t* __restrict__ whB, float* __restrict__ s1b, float* __restrict__ s2g,
    float* __restrict__ smaxrg)
{
    __shared__ float sred[4][16][2];
    const int tid = threadIdx.x;
    const int w = tid >> 6, lane = tid & 63;
    const int q = lane >> 4, n16 = lane & 15;
    const int R0 = blockIdx.x * 16;
    const int f0 = w * 32;

    f32x4 acc[2];
    acc[0] = 0.f; acc[1] = 0.f;

    const float* hrow = h + (size_t)(R0 + n16) * 128 + q * 8;
    const uint16_t* whbase = whi_ + (size_t)(f0 + n16) * 128 + q * 8;
    const uint16_t* wlbase = wlo_ + (size_t)(f0 + n16) * 128 + q * 8;
#pragma unroll
    for (int kc = 0; kc < 4; ++kc) {
        float4 x0 = *(const float4*)(hrow + kc * 32);
        float4 x1 = *(const float4*)(hrow + kc * 32 + 4);
        float xs[8] = {x0.x, x0.y, x0.z, x0.w, x1.x, x1.y, x1.z, x1.w};
        s16x8 ahi, alo;
#pragma unroll
        for (int t = 0; t < 8; ++t) {
            uint16_t hb = f2bf(xs[t]);
            ahi[t] = (short)hb;
            alo[t] = (short)f2bf(xs[t] - bf2f(hb));
        }
#pragma unroll
        for (int fb = 0; fb < 2; ++fb) {
            s16x8 bhi = *(const s16x8*)(whbase + fb * 16 * 128 + kc * 32);
            s16x8 blo = *(const s16x8*)(wlbase + fb * 16 * 128 + kc * 32);
            acc[fb] = __builtin_amdgcn_mfma_f32_16x16x32_bf16(ahi, bhi, acc[fb], 0, 0, 0);
            acc[fb] = __builtin_amdgcn_mfma_f32_16x16x32_bf16(alo, bhi, acc[fb], 0, 0, 0);
            acc[fb] = __builtin_amdgcn_mfma_f32_16x16x32_bf16(ahi, blo, acc[fb], 0, 0, 0);
        }
    }

    // s1/s2 partials over this wave's 32 f (cols = n16 within each fb)
    float s1p[4] = {0.f, 0.f, 0.f, 0.f}, s2p[4] = {0.f, 0.f, 0.f, 0.f};
#pragma unroll
    for (int fb = 0; fb < 2; ++fb) {
        float a1 = aw[f0 + fb * 16 + n16];
        float a2 = aw[128 + f0 + fb * 16 + n16];
#pragma unroll
        for (int reg = 0; reg < 4; ++reg) {
            s1p[reg] = fmaf(acc[fb][reg], a1, s1p[reg]);
            s2p[reg] = fmaf(acc[fb][reg], a2, s2p[reg]);
        }
    }
#pragma unroll
    for (int off = 1; off < 16; off <<= 1) {
#pragma unroll
        for (int reg = 0; reg < 4; ++reg) {
            s1p[reg] += __shfl_xor(s1p[reg], off);
            s2p[reg] += __shfl_xor(s2p[reg], off);
        }
    }
    if (n16 == 0) {
#pragma unroll
        for (int reg = 0; reg < 4; ++reg) {
            sred[w][q * 4 + reg][0] = s1p[reg];
            sred[w][q * 4 + reg][1] = s2p[reg];
        }
    }
    __syncthreads();
    if (tid < 16) {
        float s1 = sred[0][tid][0] + sred[1][tid][0] + sred[2][tid][0] + sred[3][tid][0];
        float s2 = sred[0][tid][1] + sred[1][tid][1] + sred[2][tid][1] + sred[3][tid][1];
        int R = R0 + tid;
        s1b[R] = LOG2E * (s1 + ab[0]);
        float s2s = LOG2E * s2;
        s2g[R] = s2s;
        float m = s2s;
#pragma unroll
        for (int off = 1; off < 16; off <<= 1)
            m = fmaxf(m, __shfl_xor(m, off));
        if (tid == 0) smaxrg[blockIdx.x] = m;   // per-rowgroup s2 max
    }

    // whB store: D-elem (i=q*4+reg, f=f0+fb*16+n16) -> bf16 at frag-order address
    const int b = R0 >> 10;
    const int jt = (R0 & 1023) >> 5;
    const int rg1 = (R0 >> 4) & 1;
    uint16_t* base = whB + (size_t)b * 131072 + (size_t)jt * 512;
    const int lane8p = (rg1 * 2 + (q >> 1)) * 16 + n16;
#pragma unroll
    for (int fb = 0; fb < 2; ++fb) {
        int fblk = w * 2 + fb;
        uint32_t e0 = f2bf(acc[fb][0]), e1 = f2bf(acc[fb][1]);
        uint32_t e2 = f2bf(acc[fb][2]), e3 = f2bf(acc[fb][3]);
        uint2 val = make_uint2(e0 | (e1 << 16), e2 | (e3 << 16));
        *(uint2*)(base + fblk * 16384 + lane8p * 8 + (q & 1) * 4) = val;
    }
}

// -------------------- Kernel 2: fused attention, barrier-free, 16 waves/CU --------------------
// 4096 blocks x 64 thr. XCD-swizzled decode: xcd=idx&7 -> batches {2*xcd, 2*xcd+1} stay on one
// XCD's L2 (512 KB B-slice). Block = rowgroup (16 rows) x f-quarter (32 f), sweeps 1024 j.
// Plain batch max (no diag exclusion): softmax shift-invariance makes the ratio exact.
__global__ __launch_bounds__(64) void k2_attn(
    const uint16_t* __restrict__ whB, const float* __restrict__ s1b,
    const float* __restrict__ s2g, const float* __restrict__ smaxrg,
    float* __restrict__ out)
{
    const int lane = threadIdx.x;
    const int q = lane >> 4, n16 = lane & 15;
    const int idx = blockIdx.x;
    const int xcd = idx & 7, o = idx >> 3;
    const int b = xcd * 2 + (o >> 8);
    const int rem = o & 255;
    const int fq = rem >> 6, rg = rem & 63;
    const int rowbase = b * 1024 + rg * 16;
    const int jb = b * 1024;

    // batch max of s2 from the 64 rowgroup maxima
    float M = smaxrg[b * 64 + lane];
#pragma unroll
    for (int off = 1; off < 64; off <<= 1)
        M = fmaxf(M, __shfl_xor(M, off));

    const int iRow = rowbase + n16;      // this lane's A-row (global)
    const int ji = iRow & 1023;          // within-batch (diag mask)
    const float s1v = s1b[iRow];
    const float tm = s1v + M;
    const float mi = fmaxf(tm, 0.2f * tm);  // leaky(tm) >= row max (log2 domain)
    const float Ai = s1v - mi;
    const float Bi = fmaf(0.2f, s1v, -mi);
    float l = 0.f;
    f32x4 acc[2];
    acc[0] = 0.f; acc[1] = 0.f;

    const uint16_t* wb = whB + (size_t)b * 131072 + (size_t)lane * 8;
    const float* ug = s2g + jb + q * 8;

    for (int jt = 0; jt < 32; ++jt) {
        const int J0 = jt * 32;
        float4 ua = *(const float4*)(ug + J0);
        float4 ub = *(const float4*)(ug + J0 + 4);
        float uv[8] = {ua.x, ua.y, ua.z, ua.w, ub.x, ub.y, ub.z, ub.w};
        s16x8 A;
#pragma unroll
        for (int t = 0; t < 8; ++t) {
            float arg = fmaxf(Ai + uv[t], fmaf(0.2f, uv[t], Bi));
            float p = __builtin_amdgcn_exp2f(arg);
            if (J0 + q * 8 + t == ji) p = 0.f;   // diagonal mask
            uint16_t pb = f2bf(p);
            l += bf2f(pb);                        // denominator from rounded p
            A[t] = (short)pb;
        }
        const uint16_t* bp = wb + (size_t)jt * 512;
#pragma unroll
        for (int fb = 0; fb < 2; ++fb) {
            s16x8 B = *(const s16x8*)(bp + (size_t)(fq * 2 + fb) * 16384);
            acc[fb] = __builtin_amdgcn_mfma_f32_16x16x32_bf16(A, B, acc[fb], 0, 0, 0);
        }
    }

    // fold quad partials of l (per-lane l covers row n16, j-slice q)
    l += __shfl_xor(l, 16);
    l += __shfl_xor(l, 32);
    float rl[4];
#pragma unroll
    for (int reg = 0; reg < 4; ++reg)
        rl[reg] = 1.0f / __shfl(l, q * 4 + reg);  // D rows are m = q*4+reg

    const int f0 = fq * 32;
#pragma unroll
    for (int fb = 0; fb < 2; ++fb) {
#pragma unroll
        for (int reg = 0; reg < 4; ++reg) {
            float v = acc[fb][reg] * rl[reg];
            float e = v > 0.f ? v : (__builtin_amdgcn_exp2f(v * LOG2E) - 1.f);
            int row = rowbase + q * 4 + reg;
            out[(size_t)row * 128 + f0 + fb * 16 + n16] = e;
        }
    }
}

extern "C" void kernel_launch(void* const* d_in, const int* in_sizes, int n_in,
                              void* d_out, int out_size, void* d_ws, size_t ws_size,
                              hipStream_t stream) {
    (void)in_sizes; (void)n_in; (void)out_size; (void)ws_size;
    const float* h  = (const float*)d_in[0];
    const float* W  = (const float*)d_in[1];
    const float* aw = (const float*)d_in[2];
    const float* ab = (const float*)d_in[3];
    float* out = (float*)d_out;

    uint16_t* whB = (uint16_t*)d_ws;                       // 16 x 131072 bf16 = 4 MB
    float* s1b    = (float*)((char*)d_ws + (4u << 20));    // 16384 f32
    float* s2g    = s1b + 16384;                           // 16384 f32
    float* smaxrg = s2g + 16384;                           // 1024 f32 (per-rowgroup s2 max)
    uint16_t* whi = (uint16_t*)(smaxrg + 1024);            // 128x128 bf16
    uint16_t* wlo = whi + 16384;                           // 128x128 bf16

    k0_splitW<<<64, 256, 0, stream>>>(W, whi, wlo);
    k1_gemm<<<1024, 256, 0, stream>>>(h, whi, wlo, aw, ab, whB, s1b, s2g, smaxrg);
    k2_attn<<<4096, 64, 0, stream>>>(whB, s1b, s2g, smaxrg, out);
}

// Round 8
// 99.229 us; speedup vs baseline: 1.0718x; 1.0718x over previous
//
#include <hip/hip_runtime.h>
#include <hip/hip_bf16.h>
#include <stdint.h>

#define LOG2E 1.4426950408889634f

typedef float f32x4 __attribute__((ext_vector_type(4)));
typedef short s16x8 __attribute__((ext_vector_type(8)));
typedef int   i32x4 __attribute__((ext_vector_type(4)));

__device__ __forceinline__ float bf2f(uint16_t u) {
    uint32_t x = ((uint32_t)u) << 16;
    float f;
    __builtin_memcpy(&f, &x, 4);
    return f;
}
__device__ __forceinline__ uint16_t f2bf(float f) {
    uint32_t x;
    __builtin_memcpy(&x, &f, 4);
    uint32_t r = (x + 0x7fffu + ((x >> 16) & 1u)) >> 16;
    return (uint16_t)r;
}

// -------------------- Kernel 0: split W (fp32) into hi/lo bf16 --------------------
__global__ __launch_bounds__(256) void k0_splitW(
    const float* __restrict__ W, uint16_t* __restrict__ whi, uint16_t* __restrict__ wlo)
{
    int i = blockIdx.x * 256 + threadIdx.x;
    float x = W[i];
    uint16_t hb = f2bf(x);
    whi[i] = hb;
    wlo[i] = f2bf(x - bf2f(hb));
}

// -------------------- Kernel 1: Wh via split-bf16 MFMA; whB frag-order; s1/s2; rowgroup max ---
// (unchanged from round 7 — verified passing)
__global__ __launch_bounds__(256) void k1_gemm(
    const float* __restrict__ h, const uint16_t* __restrict__ whi_,
    const uint16_t* __restrict__ wlo_,
    const float* __restrict__ aw, const float* __restrict__ ab,
    uint16_t* __restrict__ whB, float* __restrict__ s1b, float* __restrict__ s2g,
    float* __restrict__ smaxrg)
{
    __shared__ float sred[4][16][2];
    const int tid = threadIdx.x;
    const int w = tid >> 6, lane = tid & 63;
    const int q = lane >> 4, n16 = lane & 15;
    const int R0 = blockIdx.x * 16;
    const int f0 = w * 32;

    f32x4 acc[2];
    acc[0] = 0.f; acc[1] = 0.f;

    const float* hrow = h + (size_t)(R0 + n16) * 128 + q * 8;
    const uint16_t* whbase = whi_ + (size_t)(f0 + n16) * 128 + q * 8;
    const uint16_t* wlbase = wlo_ + (size_t)(f0 + n16) * 128 + q * 8;
#pragma unroll
    for (int kc = 0; kc < 4; ++kc) {
        float4 x0 = *(const float4*)(hrow + kc * 32);
        float4 x1 = *(const float4*)(hrow + kc * 32 + 4);
        float xs[8] = {x0.x, x0.y, x0.z, x0.w, x1.x, x1.y, x1.z, x1.w};
        s16x8 ahi, alo;
#pragma unroll
        for (int t = 0; t < 8; ++t) {
            uint16_t hb = f2bf(xs[t]);
            ahi[t] = (short)hb;
            alo[t] = (short)f2bf(xs[t] - bf2f(hb));
        }
#pragma unroll
        for (int fb = 0; fb < 2; ++fb) {
            s16x8 bhi = *(const s16x8*)(whbase + fb * 16 * 128 + kc * 32);
            s16x8 blo = *(const s16x8*)(wlbase + fb * 16 * 128 + kc * 32);
            acc[fb] = __builtin_amdgcn_mfma_f32_16x16x32_bf16(ahi, bhi, acc[fb], 0, 0, 0);
            acc[fb] = __builtin_amdgcn_mfma_f32_16x16x32_bf16(alo, bhi, acc[fb], 0, 0, 0);
            acc[fb] = __builtin_amdgcn_mfma_f32_16x16x32_bf16(ahi, blo, acc[fb], 0, 0, 0);
        }
    }

    float s1p[4] = {0.f, 0.f, 0.f, 0.f}, s2p[4] = {0.f, 0.f, 0.f, 0.f};
#pragma unroll
    for (int fb = 0; fb < 2; ++fb) {
        float a1 = aw[f0 + fb * 16 + n16];
        float a2 = aw[128 + f0 + fb * 16 + n16];
#pragma unroll
        for (int reg = 0; reg < 4; ++reg) {
            s1p[reg] = fmaf(acc[fb][reg], a1, s1p[reg]);
            s2p[reg] = fmaf(acc[fb][reg], a2, s2p[reg]);
        }
    }
#pragma unroll
    for (int off = 1; off < 16; off <<= 1) {
#pragma unroll
        for (int reg = 0; reg < 4; ++reg) {
            s1p[reg] += __shfl_xor(s1p[reg], off);
            s2p[reg] += __shfl_xor(s2p[reg], off);
        }
    }
    if (n16 == 0) {
#pragma unroll
        for (int reg = 0; reg < 4; ++reg) {
            sred[w][q * 4 + reg][0] = s1p[reg];
            sred[w][q * 4 + reg][1] = s2p[reg];
        }
    }
    __syncthreads();
    if (tid < 16) {
        float s1 = sred[0][tid][0] + sred[1][tid][0] + sred[2][tid][0] + sred[3][tid][0];
        float s2 = sred[0][tid][1] + sred[1][tid][1] + sred[2][tid][1] + sred[3][tid][1];
        int R = R0 + tid;
        s1b[R] = LOG2E * (s1 + ab[0]);
        float s2s = LOG2E * s2;
        s2g[R] = s2s;
        float m = s2s;
#pragma unroll
        for (int off = 1; off < 16; off <<= 1)
            m = fmaxf(m, __shfl_xor(m, off));
        if (tid == 0) smaxrg[blockIdx.x] = m;
    }

    const int b = R0 >> 10;
    const int jt = (R0 & 1023) >> 5;
    const int rg1 = (R0 >> 4) & 1;
    uint16_t* base = whB + (size_t)b * 131072 + (size_t)jt * 512;
    const int lane8p = (rg1 * 2 + (q >> 1)) * 16 + n16;
#pragma unroll
    for (int fb = 0; fb < 2; ++fb) {
        int fblk = w * 2 + fb;
        uint32_t e0 = f2bf(acc[fb][0]), e1 = f2bf(acc[fb][1]);
        uint32_t e2 = f2bf(acc[fb][2]), e3 = f2bf(acc[fb][3]);
        uint2 val = make_uint2(e0 | (e1 << 16), e2 | (e3 << 16));
        *(uint2*)(base + fblk * 16384 + lane8p * 8 + (q & 1) * 4) = val;
    }
}

// -------------------- Kernel 2: fused attention v3 ---------------------------------------------
// 2048 blocks x 1 wave. Block = 32 rows x 32 f, sweeps 1024 j. XCD-swizzled (xcd = idx&7).
// - l from ones-MFMA (row sums land in acc layout; zero shuffles)
// - diag handled by post-loop subtraction (no per-element mask)
// - A pack by fp32-bit truncation (bias cancels in softmax ratio)
// - B double-buffered one j-tile ahead
__global__ __launch_bounds__(64) void k2_attn(
    const uint16_t* __restrict__ whB, const float* __restrict__ s1b,
    const float* __restrict__ s2g, const float* __restrict__ smaxrg,
    float* __restrict__ out)
{
    const int lane = threadIdx.x;
    const int q = lane >> 4, n16 = lane & 15;
    const int idx = blockIdx.x;
    const int xcd = idx & 7;
    const int o = idx >> 3;              // [0,256)
    const int b = ((o >> 7) << 3) | xcd; // batches {xcd, xcd+8} stay on one XCD's L2
    const int rem = o & 127;
    const int rg = rem >> 2;             // rowgroup of 32 rows
    const int fq = rem & 3;              // f-quarter (32 f)
    const int jb = b << 10;
    const int iw0 = rg * 32;
    const int f0 = fq * 32;

    // batch max of s2 (plain max; softmax shift-invariance keeps ratio exact)
    float M = smaxrg[(b << 6) | lane];
#pragma unroll
    for (int off = 1; off < 64; off <<= 1)
        M = fmaxf(M, __shfl_xor(M, off));

    // per-lane A-row constants for rowfrags rf=0,1 (rows iw0 + rf*16 + n16)
    float Ai[2], Bi[2];
#pragma unroll
    for (int rf = 0; rf < 2; ++rf) {
        float s1v = s1b[jb + iw0 + rf * 16 + n16];
        float tm = s1v + M;
        float mi = fmaxf(tm, 0.2f * tm);
        Ai[rf] = s1v - mi;
        Bi[rf] = fmaf(0.2f, s1v, -mi);
    }

    f32x4 acc[2][2], accl[2];
#pragma unroll
    for (int rf = 0; rf < 2; ++rf) {
        acc[rf][0] = 0.f; acc[rf][1] = 0.f; accl[rf] = 0.f;
    }

    s16x8 Bones;
#pragma unroll
    for (int t = 0; t < 8; ++t) Bones[t] = (short)0x3F80;  // bf16(1.0)

    const uint16_t* wb = whB + ((size_t)b << 17) + lane * 8;
    const float* ug = s2g + jb + q * 8;
    const int fblk0 = fq * 2, fblk1 = fq * 2 + 1;

    s16x8 Bc0 = *(const s16x8*)(wb + fblk0 * 16384);
    s16x8 Bc1 = *(const s16x8*)(wb + fblk1 * 16384);

    for (int jt = 0; jt < 32; ++jt) {
        const int jn = (jt < 31) ? jt + 1 : 31;
        const uint16_t* bpn = wb + jn * 512;
        s16x8 Bn0 = *(const s16x8*)(bpn + fblk0 * 16384);
        s16x8 Bn1 = *(const s16x8*)(bpn + fblk1 * 16384);

        float4 ua = *(const float4*)(ug + jt * 32);
        float4 ub = *(const float4*)(ug + jt * 32 + 4);
        float uv[8] = {ua.x, ua.y, ua.z, ua.w, ub.x, ub.y, ub.z, ub.w};

        s16x8 A[2];
#pragma unroll
        for (int rf = 0; rf < 2; ++rf) {
            i32x4 pk;
#pragma unroll
            for (int pr = 0; pr < 4; ++pr) {
                float p0 = __builtin_amdgcn_exp2f(
                    fmaxf(Ai[rf] + uv[2 * pr], fmaf(0.2f, uv[2 * pr], Bi[rf])));
                float p1 = __builtin_amdgcn_exp2f(
                    fmaxf(Ai[rf] + uv[2 * pr + 1], fmaf(0.2f, uv[2 * pr + 1], Bi[rf])));
                pk[pr] = (int)((__builtin_bit_cast(uint32_t, p0) >> 16) |
                               (__builtin_bit_cast(uint32_t, p1) & 0xffff0000u));
            }
            A[rf] = __builtin_bit_cast(s16x8, pk);
        }
#pragma unroll
        for (int rf = 0; rf < 2; ++rf) {
            acc[rf][0] = __builtin_amdgcn_mfma_f32_16x16x32_bf16(A[rf], Bc0, acc[rf][0], 0, 0, 0);
            acc[rf][1] = __builtin_amdgcn_mfma_f32_16x16x32_bf16(A[rf], Bc1, acc[rf][1], 0, 0, 0);
            accl[rf]   = __builtin_amdgcn_mfma_f32_16x16x32_bf16(A[rf], Bones, accl[rf], 0, 0, 0);
        }
        Bc0 = Bn0; Bc1 = Bn1;
    }

    // post-loop diagonal subtraction: rows this lane holds are iw0 + rf*16 + q*4 + reg
#pragma unroll
    for (int rf = 0; rf < 2; ++rf) {
#pragma unroll
        for (int reg = 0; reg < 4; ++reg) {
            int iw = iw0 + rf * 16 + q * 4 + reg;
            float s1v = s1b[jb + iw];
            float tm = s1v + M;
            float mi = fmaxf(tm, 0.2f * tm);
            float u_i = s2g[jb + iw];
            float arg = fmaxf((s1v - mi) + u_i, fmaf(0.2f, u_i, fmaf(0.2f, s1v, -mi)));
            float p = __builtin_amdgcn_exp2f(arg);
            float pt = __builtin_bit_cast(float, __builtin_bit_cast(uint32_t, p) & 0xffff0000u);
            accl[rf][reg] -= pt;
            int lane_i = ((iw >> 3) & 3) * 16 + n16;
#pragma unroll
            for (int fb = 0; fb < 2; ++fb) {
                size_t a = ((size_t)b << 17) + (size_t)(fq * 2 + fb) * 16384 +
                           (size_t)(iw >> 5) * 512 + lane_i * 8 + (iw & 7);
                float wv = bf2f(whB[a]);
                acc[rf][fb][reg] -= pt * wv;
            }
        }
    }

    // epilogue: scale by 1/l (in-layout, no shuffles), elu, store fp32
#pragma unroll
    for (int rf = 0; rf < 2; ++rf) {
#pragma unroll
        for (int reg = 0; reg < 4; ++reg) {
            float rl = 1.0f / accl[rf][reg];
            int row = jb + iw0 + rf * 16 + q * 4 + reg;
#pragma unroll
            for (int fb = 0; fb < 2; ++fb) {
                float v = acc[rf][fb][reg] * rl;
                float e = v > 0.f ? v : (__builtin_amdgcn_exp2f(v * LOG2E) - 1.f);
                out[(size_t)row * 128 + f0 + fb * 16 + n16] = e;
            }
        }
    }
}

extern "C" void kernel_launch(void* const* d_in, const int* in_sizes, int n_in,
                              void* d_out, int out_size, void* d_ws, size_t ws_size,
                              hipStream_t stream) {
    (void)in_sizes; (void)n_in; (void)out_size; (void)ws_size;
    const float* h  = (const float*)d_in[0];
    const float* W  = (const float*)d_in[1];
    const float* aw = (const float*)d_in[2];
    const float* ab = (const float*)d_in[3];
    float* out = (float*)d_out;

    uint16_t* whB = (uint16_t*)d_ws;                       // 16 x 131072 bf16 = 4 MB
    float* s1b    = (float*)((char*)d_ws + (4u << 20));    // 16384 f32
    float* s2g    = s1b + 16384;                           // 16384 f32
    float* smaxrg = s2g + 16384;                           // 1024 f32
    uint16_t* whi = (uint16_t*)(smaxrg + 1024);            // 128x128 bf16
    uint16_t* wlo = whi + 16384;                           // 128x128 bf16

    k0_splitW<<<64, 256, 0, stream>>>(W, whi, wlo);
    k1_gemm<<<1024, 256, 0, stream>>>(h, whi, wlo, aw, ab, whB, s1b, s2g, smaxrg);
    k2_attn<<<2048, 64, 0, stream>>>(whB, s1b, s2g, smaxrg, out);
}